// Round 9
// baseline (297.449 us; speedup 1.0000x reference)
//
#include <hip/hip_runtime.h>
#include <hip/hip_bf16.h>

// B=32, S=2048, H=512, fp32 in/out.
// scores = tanh(Y@W + b).w -> softmax(S) -> c_star = alpha@Y
// FULLY FUSED flash-style: 512 blocks, one per 128-row slab of (b,s).
// Phase 1: score GEMM, 8 n-tiles of 64 cols; Wt tile (64x512 fp16, 64KB)
//   staged in LDS per tile, FRAGMENT-ORDERED (1KB frag-blocks, lane-
//   contiguous llds dest and ds_read -> 0 bank conflicts, verified r3/r4).
//   A loaded from Y ONCE during nt=0 (global->reg->fp16), kept in 32 VGPRs
//   per lane; nt 1..7 run from registers.
// Phase 2: block-local softmax partial (m_blk, sum_blk, p=exp(s-m_blk)).
// Phase 3: U[512] = sum_rows p*Y from the SAME A registers (no Y re-read).
// combine_k: exact flash merge of 16 slab-partials per batch -> out.
// NOTE: no min-waves launch bound -- round-8's (256,2) capped VGPR at 128
// and spilled 26MB/dispatch to scratch (WRITE_SIZE smoking gun).

#define Bsz 32
#define Ssz 2048
#define Hsz 512
#define Msz (Bsz * Ssz)   // 65536

using half8   = __attribute__((ext_vector_type(8))) _Float16;
using floatx4 = __attribute__((ext_vector_type(4))) float;

__device__ __forceinline__ void llds16(void* l, const void* g) {
  __builtin_amdgcn_global_load_lds((const __attribute__((address_space(1))) void*)g,
                                   (__attribute__((address_space(3))) void*)l, 16, 0, 0);
}

__device__ __forceinline__ float fast_tanh(float x) {
  const float e = __expf(2.f * x);
  return 1.f - 2.f / (e + 1.f);
}

// ---- W[k][n] fp32 -> Wt[n][k] fp16 (transpose + RNE cast) ----
__global__ __launch_bounds__(256) void wsplit_k(const float* __restrict__ W,
                                                _Float16* __restrict__ Wt) {
  __shared__ float tile[32][33];
  const int bx = blockIdx.x & 15, by = blockIdx.x >> 4;
  const int tx = threadIdx.x & 31, ty = threadIdx.x >> 5;
#pragma unroll
  for (int i = 0; i < 4; ++i)
    tile[ty + 8 * i][tx] = W[(size_t)(by * 32 + ty + 8 * i) * Hsz + bx * 32 + tx];
  __syncthreads();
#pragma unroll
  for (int i = 0; i < 4; ++i) {
    const int n = bx * 32 + ty + 8 * i;
    const int k = by * 32 + tx;
    Wt[(size_t)n * Hsz + k] = (_Float16)tile[tx][ty + 8 * i];
  }
}

// ---- fused: scores + block softmax partial + weighted sum partial ----
__global__ __launch_bounds__(256) void fused_k(const float* __restrict__ Y,
                                               const _Float16* __restrict__ Wt,
                                               const float* __restrict__ bvec,
                                               const float* __restrict__ wvec,
                                               const float* __restrict__ mask,
                                               float* __restrict__ pU,
                                               float* __restrict__ pM,
                                               float* __restrict__ pS) {
  // Fragment-ordered Wt tile: frag-block fb = ks*4+cf (1KB each): lane l
  // holds Wt[nt*64 + cf*16 + (l&15)][ks*32 + (l>>4)*8 .. +8]  (16B).
  // Stage dest &Bs[fb*512]+lane*16 (linear), read &Bs[fb*512]+lane*16:
  // both lane-contiguous -> 0 bank conflicts (verified rounds 3/4).
  __shared__ __align__(16) _Float16 Bs[64 * 512];   // 64 KB
  __shared__ float U_lds[4][512];                   // 8 KB per-wave U partials
  __shared__ float s_lds[128], p_lds[128];
  __shared__ float rm[4], rs[4];

  const int tid = threadIdx.x;
  const int lane = tid & 63, wv = tid >> 6;
  const int lr = lane & 15, lq = lane >> 4;
  const int blk = blockIdx.x;          // 0..511
  const int row0 = blk * 128;          // global (b,s) row base

  // A rows for this lane: local rows wv*32+lr and wv*32+16+lr; k-slice lq*8..+8
  // per k-step (verified A-frag lane mapping: row=..+lr, k=k0+lq*8).
  const float* aR0 = Y + (size_t)(row0 + wv * 32 + lr) * Hsz + lq * 8;
  const float* aR1 = aR0 + (size_t)16 * Hsz;

  half8 a0[16], a1[16];   // A held fp16 for all 16 k-steps (32 VGPR)
  float sc[2][4];         // per-row score partials [rf][r]
#pragma unroll
  for (int rf = 0; rf < 2; ++rf)
#pragma unroll
    for (int r = 0; r < 4; ++r) sc[rf][r] = 0.f;

#pragma unroll 1
  for (int nt = 0; nt < 8; ++nt) {
    // Stage Wt tile nt: 64 frag-blocks / 4 waves = 16 llds per thread.
#pragma unroll
    for (int i = 0; i < 16; ++i) {
      const int fb = wv * 16 + i;                  // wave-uniform
      const int ks = fb >> 2, cf = fb & 3;
      llds16(&Bs[(size_t)fb * 512],
             Wt + (size_t)(nt * 64 + cf * 16 + lr) * Hsz + ks * 32 + lq * 8);
    }
    __syncthreads();

    floatx4 acc[2][4];
#pragma unroll
    for (int rf = 0; rf < 2; ++rf)
#pragma unroll
      for (int cf = 0; cf < 4; ++cf)
        acc[rf][cf] = (floatx4){0.f, 0.f, 0.f, 0.f};

    if (nt == 0) {
      // A streams from HBM here (once), cvt fp16, cached in regs.
#pragma unroll
      for (int kk = 0; kk < 16; ++kk) {
        const float4 f00 = *(const float4*)(aR0 + kk * 32);
        const float4 f01 = *(const float4*)(aR0 + kk * 32 + 4);
        const float4 f10 = *(const float4*)(aR1 + kk * 32);
        const float4 f11 = *(const float4*)(aR1 + kk * 32 + 4);
        half8 h0, h1;
        h0[0] = (_Float16)f00.x; h0[1] = (_Float16)f00.y;
        h0[2] = (_Float16)f00.z; h0[3] = (_Float16)f00.w;
        h0[4] = (_Float16)f01.x; h0[5] = (_Float16)f01.y;
        h0[6] = (_Float16)f01.z; h0[7] = (_Float16)f01.w;
        h1[0] = (_Float16)f10.x; h1[1] = (_Float16)f10.y;
        h1[2] = (_Float16)f10.z; h1[3] = (_Float16)f10.w;
        h1[4] = (_Float16)f11.x; h1[5] = (_Float16)f11.y;
        h1[6] = (_Float16)f11.z; h1[7] = (_Float16)f11.w;
        a0[kk] = h0; a1[kk] = h1;
#pragma unroll
        for (int cf = 0; cf < 4; ++cf) {
          const half8 bf = *(const half8*)&Bs[(size_t)(kk * 4 + cf) * 512 + lane * 8];
          acc[0][cf] = __builtin_amdgcn_mfma_f32_16x16x32_f16(h0, bf, acc[0][cf], 0, 0, 0);
          acc[1][cf] = __builtin_amdgcn_mfma_f32_16x16x32_f16(h1, bf, acc[1][cf], 0, 0, 0);
        }
      }
    } else {
      // Pure reg + LDS: compiler free to interleave ds_read/MFMA.
#pragma unroll
      for (int kk = 0; kk < 16; ++kk) {
#pragma unroll
        for (int cf = 0; cf < 4; ++cf) {
          const half8 bf = *(const half8*)&Bs[(size_t)(kk * 4 + cf) * 512 + lane * 8];
          acc[0][cf] = __builtin_amdgcn_mfma_f32_16x16x32_f16(a0[kk], bf, acc[0][cf], 0, 0, 0);
          acc[1][cf] = __builtin_amdgcn_mfma_f32_16x16x32_f16(a1[kk], bf, acc[1][cf], 0, 0, 0);
        }
      }
    }

    // Score partial for this 64-col slice: v = sum_cf tanh(pre+b)*w,
    // shuffle-reduced over the 16 col-lanes (verified epilogue pattern).
    float bb[4], ww[4];
#pragma unroll
    for (int cf = 0; cf < 4; ++cf) {
      const int col = nt * 64 + cf * 16 + lr;
      bb[cf] = bvec[col];
      ww[cf] = wvec[col];
    }
#pragma unroll
    for (int rf = 0; rf < 2; ++rf) {
#pragma unroll
      for (int r = 0; r < 4; ++r) {
        float v = 0.f;
#pragma unroll
        for (int cf = 0; cf < 4; ++cf)
          v += fast_tanh(acc[rf][cf][r] + bb[cf]) * ww[cf];
        v += __shfl_xor(v, 1, 16);
        v += __shfl_xor(v, 2, 16);
        v += __shfl_xor(v, 4, 16);
        v += __shfl_xor(v, 8, 16);
        sc[rf][r] += v;
      }
    }
    __syncthreads();   // all Bs reads done before next tile's staging
  }

  // ---- Phase 2: block-local softmax partial over the 128 rows ----
  if (lr == 0) {
#pragma unroll
    for (int rf = 0; rf < 2; ++rf)
#pragma unroll
      for (int r = 0; r < 4; ++r)
        s_lds[wv * 32 + rf * 16 + lq * 4 + r] = sc[rf][r];
  }
  __syncthreads();
  float v = -3.4e38f;
  if (tid < 128) v = s_lds[tid] - 1000.f * (1.f - mask[row0 + tid]);
  float m = v;
  for (int off = 32; off > 0; off >>= 1) m = fmaxf(m, __shfl_xor(m, off, 64));
  if (lane == 0) rm[wv] = m;
  __syncthreads();
  m = fmaxf(fmaxf(rm[0], rm[1]), fmaxf(rm[2], rm[3]));
  float p = (tid < 128) ? __expf(v - m) : 0.f;
  if (tid < 128) p_lds[tid] = p;
  float sum = p;
  for (int off = 32; off > 0; off >>= 1) sum += __shfl_xor(sum, off, 64);
  if (lane == 0) rs[wv] = sum;
  __syncthreads();
  sum = rs[0] + rs[1] + rs[2] + rs[3];

  // ---- Phase 3: U = sum_rows p*Y from the A registers (no Y re-read) ----
  const float p0 = p_lds[wv * 32 + lr];
  const float p1 = p_lds[wv * 32 + 16 + lr];
#pragma unroll
  for (int kk = 0; kk < 16; ++kk) {
    float u[8];
#pragma unroll
    for (int j = 0; j < 8; ++j)
      u[j] = p0 * (float)a0[kk][j] + p1 * (float)a1[kk][j];
#pragma unroll
    for (int off = 1; off < 16; off <<= 1)
#pragma unroll
      for (int j = 0; j < 8; ++j) u[j] += __shfl_xor(u[j], off, 16);
    if (lr == 0) {
      *(float4*)&U_lds[wv][kk * 32 + lq * 8]     = (float4){u[0], u[1], u[2], u[3]};
      *(float4*)&U_lds[wv][kk * 32 + lq * 8 + 4] = (float4){u[4], u[5], u[6], u[7]};
    }
  }
  __syncthreads();
#pragma unroll
  for (int i = 0; i < 2; ++i) {
    const int h = i * 256 + tid;
    pU[(size_t)blk * Hsz + h] =
        U_lds[0][h] + U_lds[1][h] + U_lds[2][h] + U_lds[3][h];
  }
  if (tid == 0) { pM[blk] = m; pS[blk] = sum; }
}

// ---- combine: exact flash merge of 16 slab-partials per batch ----
__global__ __launch_bounds__(256) void combine_k(const float* __restrict__ pU,
                                                 const float* __restrict__ pM,
                                                 const float* __restrict__ pS,
                                                 float* __restrict__ out) {
  const int b = blockIdx.x, t = threadIdx.x;
  float m = -3.4e38f;
#pragma unroll
  for (int j = 0; j < 16; ++j) m = fmaxf(m, pM[b * 16 + j]);
  float D = 0.f, u0 = 0.f, u1 = 0.f;
#pragma unroll
  for (int j = 0; j < 16; ++j) {
    const float e = __expf(pM[b * 16 + j] - m);
    D  += e * pS[b * 16 + j];
    u0 += e * pU[(size_t)(b * 16 + j) * Hsz + t];
    u1 += e * pU[(size_t)(b * 16 + j) * Hsz + 256 + t];
  }
  const float inv = 1.f / D;
  out[b * Hsz + t]       = u0 * inv;
  out[b * Hsz + 256 + t] = u1 * inv;
}

extern "C" void kernel_launch(void* const* d_in, const int* in_sizes, int n_in,
                              void* d_out, int out_size, void* d_ws, size_t ws_size,
                              hipStream_t stream) {
  (void)in_sizes; (void)n_in; (void)out_size; (void)ws_size;
  const float* Y    = (const float*)d_in[0];
  const float* mask = (const float*)d_in[1];
  const float* W    = (const float*)d_in[2];
  const float* bvec = (const float*)d_in[3];
  const float* wvec = (const float*)d_in[4];
  float* out = (float*)d_out;

  char* ws = (char*)d_ws;
  _Float16* Wt = (_Float16*)ws;                        // 512 KB @ 0
  float* pU    = (float*)(ws + ((size_t)1 << 20));     // 1 MB   @ 1M (512 x 512)
  float* pM    = (float*)(ws + ((size_t)2 << 20));     // 2 KB   @ 2M
  float* pS    = (float*)(ws + ((size_t)2 << 20) + 4096);

  wsplit_k<<<256, 256, 0, stream>>>(W, Wt);
  fused_k<<<512, 256, 0, stream>>>(Y, Wt, bvec, wvec, mask, pU, pM, pS);
  combine_k<<<Bsz, 256, 0, stream>>>(pU, pM, pS, out);
}